// Round 3
// baseline (272.170 us; speedup 1.0000x reference)
//
#include <hip/hip_runtime.h>

#define HDIM 4096
#define NIN 17
#define NA 4

// ---- k_matvec config ----
constexpr int TB = 256;                 // threads per block
constexpr int CPT = 4;                  // columns per thread (one float4)
constexpr int BXC = HDIM / (TB * CPT);  // 4 column groups
constexpr int NCHUNK = 512;             // row chunks  -> 2048 blocks = 8/CU = 32 waves/CU
constexpr int RPC = HDIM / NCHUNK;      // 8 rows per chunk (fully unrolled)

// Workspace layout (floats): z[4096] | res[8] | h_f[4096]
#define WS_Z 0
#define WS_RES 4096
#define WS_HF 4104

// Kernel 0: zero the atomic accumulators (d_ws is poisoned 0xAA each call)
__global__ __launch_bounds__(256)
void k_init(float* __restrict__ ws) {
    const int i = blockIdx.x * 256 + threadIdx.x;
    if (i < WS_HF) ws[i] = 0.f;
}

// Kernel A: z[j] += sum_{i in chunk} hidden[i] * (w[i,j] + alpha[i,j]*hebb[i,j])
// Fully unrolled over 8 rows -> 24 independent float4 loads in flight per thread.
__global__ __launch_bounds__(TB, 4)
void k_matvec(const float* __restrict__ w, const float* __restrict__ alpha,
              const float* __restrict__ hebb, const float* __restrict__ hidden,
              float* __restrict__ z) {
    const int col0 = (blockIdx.x * TB + threadIdx.x) * CPT;
    const int row0 = blockIdx.y * RPC;
    float4 acc = make_float4(0.f, 0.f, 0.f, 0.f);
#pragma unroll
    for (int r = 0; r < RPC; ++r) {
        const int i = row0 + r;
        const size_t off = (size_t)i * HDIM + col0;
        const float hv = hidden[i];
        const float4 wv = *(const float4*)(w + off);
        const float4 av = *(const float4*)(alpha + off);
        const float4 bv = *(const float4*)(hebb + off);
        acc.x += hv * (wv.x + av.x * bv.x);
        acc.y += hv * (wv.y + av.y * bv.y);
        acc.z += hv * (wv.z + av.z * bv.z);
        acc.w += hv * (wv.w + av.w * bv.w);
    }
    atomicAdd(z + col0 + 0, acc.x);
    atomicAdd(z + col0 + 1, acc.y);
    atomicAdd(z + col0 + 2, acc.z);
    atomicAdd(z + col0 + 3, acc.w);
}

// Kernel B: h = tanh(z + i2h(x) + b); also fused head dot-products via
// wave-shuffle reduction + one atomic per wave per output.
__global__ __launch_bounds__(256)
void k_hact(const float* __restrict__ z,
            const float* __restrict__ x, const float* __restrict__ i2h_w,
            const float* __restrict__ i2h_b,
            const float* __restrict__ h2o_w, const float* __restrict__ h2v_w,
            float* __restrict__ h_f, float* __restrict__ h_out,
            float* __restrict__ res) {
    const int j = blockIdx.x * 256 + threadIdx.x;
    float zv = z[j] + i2h_b[j];
#pragma unroll
    for (int k = 0; k < NIN; ++k) zv += x[k] * i2h_w[j * NIN + k];
    const float h = tanhf(zv);
    h_f[j] = h;
    h_out[j] = h;
    // fused heads: d[a] = h * h2o_w[a][j], d[4] = h * h2v_w[j]
    float d[NA + 1];
#pragma unroll
    for (int a = 0; a < NA; ++a) d[a] = h * h2o_w[a * HDIM + j];
    d[NA] = h * h2v_w[j];
#pragma unroll
    for (int a = 0; a < NA + 1; ++a) {
#pragma unroll
        for (int off = 32; off > 0; off >>= 1) d[a] += __shfl_down(d[a], off);
    }
    if ((threadIdx.x & 63) == 0) {
#pragma unroll
        for (int a = 0; a < NA + 1; ++a) atomicAdd(res + a, d[a]);
    }
}

// Kernel C: softmax + value from the reduced dots (trivial)
__global__ void k_finish(const float* __restrict__ res,
                         const float* __restrict__ h2o_b,
                         const float* __restrict__ h2v_b,
                         float* __restrict__ out) {
    if (threadIdx.x == 0) {
        float o[NA];
        float mx = -1e30f;
#pragma unroll
        for (int a = 0; a < NA; ++a) { o[a] = res[a] + h2o_b[a]; mx = fmaxf(mx, o[a]); }
        float se = 0.f;
#pragma unroll
        for (int a = 0; a < NA; ++a) { o[a] = __expf(o[a] - mx); se += o[a]; }
#pragma unroll
        for (int a = 0; a < NA; ++a) out[a] = o[a] / se;
        out[NA] = res[NA] + h2v_b[0];
    }
}

// Kernel D: hebb_new = (1-eta)*hebb + eta*outer(hidden, h); 4 elems/thread.
// hebb_out region is only 4B-aligned (element offset 4101) -> scalar dword stores.
__global__ __launch_bounds__(256)
void k_hebb(const float* __restrict__ hebb, const float* __restrict__ hidden,
            const float* __restrict__ h_f, const float* __restrict__ eta,
            float* __restrict__ hebb_out) {
    const size_t m = ((size_t)blockIdx.x * 256 + threadIdx.x) * 4;
    const float e = eta[0];
    const float om = 1.f - e;
    const int i = (int)(m >> 12);          // m / 4096
    const int j = (int)(m & (HDIM - 1));   // m % 4096 (multiple of 4; never crosses a row)
    const float hv = e * hidden[i];
    const float4 hb = *(const float4*)(hebb + m);
    const float4 hj = *(const float4*)(h_f + j);
    hebb_out[m]     = om * hb.x + hv * hj.x;
    hebb_out[m + 1] = om * hb.y + hv * hj.y;
    hebb_out[m + 2] = om * hb.z + hv * hj.z;
    hebb_out[m + 3] = om * hb.w + hv * hj.w;
}

extern "C" void kernel_launch(void* const* d_in, const int* in_sizes, int n_in,
                              void* d_out, int out_size, void* d_ws, size_t ws_size,
                              hipStream_t stream) {
    const float* x      = (const float*)d_in[0];
    const float* hidden = (const float*)d_in[1];
    const float* hebb   = (const float*)d_in[2];
    const float* i2h_w  = (const float*)d_in[3];
    const float* i2h_b  = (const float*)d_in[4];
    const float* w      = (const float*)d_in[5];
    const float* alpha  = (const float*)d_in[6];
    const float* eta    = (const float*)d_in[7];
    const float* h2o_w  = (const float*)d_in[8];
    const float* h2o_b  = (const float*)d_in[9];
    const float* h2v_w  = (const float*)d_in[10];
    const float* h2v_b  = (const float*)d_in[11];
    float* out = (float*)d_out;

    float* ws  = (float*)d_ws;
    float* z   = ws + WS_Z;
    float* res = ws + WS_RES;
    float* h_f = ws + WS_HF;

    // out layout: activout[4] | valueout[1] | h[4096] | hebb_new[4096*4096]
    float* h_out    = out + 5;
    float* hebb_out = out + 5 + HDIM;

    k_init<<<(WS_HF + 255) / 256, 256, 0, stream>>>(ws);
    k_matvec<<<dim3(BXC, NCHUNK), TB, 0, stream>>>(w, alpha, hebb, hidden, z);
    k_hact<<<HDIM / 256, 256, 0, stream>>>(z, x, i2h_w, i2h_b, h2o_w, h2v_w, h_f, h_out, res);
    k_finish<<<1, 64, 0, stream>>>(res, h2o_b, h2v_b, out);
    k_hebb<<<(int)(((size_t)HDIM * HDIM) / 1024), 256, 0, stream>>>(hebb, hidden, h_f, eta, hebb_out);
}